// Round 2
// baseline (131.267 us; speedup 1.0000x reference)
//
#include <hip/hip_runtime.h>
#include <hip/hip_bf16.h>

// SubjectLayers: out[b,t,o] = sum_i x[b,t,i] * w[sid[b],i,o] + bias[sid[b],o]
// B=256 T=512 IN=256 OUT=256 S=128, all fp32 in/out.
// R2: LDS-free streaming MFMA. Pre-pass transposes+converts weights to bf16
// wT[s][o][i] in d_ws (L2/L3-resident); GEMM loads A (x, f32->bf16 fused) and
// B (wT) fragments directly from global. No barriers -> compiler pipelines.

#define B_DIM 256
#define T_DIM 512
#define IN_DIM 256
#define OUT_DIM 256
#define S_DIM 128

typedef __attribute__((ext_vector_type(4))) float f32x4;
typedef __attribute__((ext_vector_type(8))) short s16x8;
typedef __attribute__((ext_vector_type(8))) unsigned short u16x8;
typedef __attribute__((ext_vector_type(4))) unsigned short u16x4;

static __device__ __forceinline__ unsigned short f2bf(float f) {
  __hip_bfloat16 h = __float2bfloat16(f);
  return __builtin_bit_cast(unsigned short, h);
}

// Pre-pass: wT[s][o][i] = bf16(w[s][i][o]). 64x64 tiles via LDS.
__global__ __launch_bounds__(256) void wt_transpose(const float* __restrict__ w,
                                                    unsigned short* __restrict__ wT) {
  __shared__ float tile[64][65];
  int bid = blockIdx.x;
  int s = bid >> 4, ti = (bid >> 2) & 3, to = bid & 3;
  const float* wp = w + (size_t)s * IN_DIM * OUT_DIM;
  unsigned short* op = wT + (size_t)s * IN_DIM * OUT_DIM;
  int t = threadIdx.x;
  int rr = t >> 6, cc = t & 63;
#pragma unroll
  for (int p = 0; p < 16; ++p) {
    tile[p * 4 + rr][cc] = wp[(size_t)(ti * 64 + p * 4 + rr) * OUT_DIM + to * 64 + cc];
  }
  __syncthreads();
  int orr = t >> 4, i4 = (t & 15) * 4;
#pragma unroll
  for (int p = 0; p < 4; ++p) {
    int ol = p * 16 + orr;  // o within tile
    u16x4 v;
    v[0] = f2bf(tile[i4 + 0][ol]);
    v[1] = f2bf(tile[i4 + 1][ol]);
    v[2] = f2bf(tile[i4 + 2][ol]);
    v[3] = f2bf(tile[i4 + 3][ol]);
    *(u16x4*)(op + (size_t)(to * 64 + ol) * IN_DIM + ti * 64 + i4) = v;
  }
}

// LDS-free GEMM. Block = 128 T-rows x 128 O-cols, 4 waves (2m x 2n),
// wave tile 64x64 as 4x4 of 16x16x32-bf16 MFMA fragments.
// A-frag: lane reads 8 consecutive f32 from x, converts to bf16x8.
// B-frag: lane reads 8 consecutive bf16 from wT (L2-resident).
__global__ __launch_bounds__(256) void subj_gemm_nl(
    const float* __restrict__ x, const int* __restrict__ sid,
    const unsigned short* __restrict__ wT, const float* __restrict__ bias,
    float* __restrict__ out) {
  // pair-swizzle so the two nt-tiles of one (batch,mt) are grid-adjacent pairs
  // landing on the same XCD (L2 reuse of x rows)
  unsigned wg = blockIdx.x;
  unsigned bid = (wg & ~15u) | ((wg & 7u) << 1) | ((wg >> 3) & 1u);
  int batch = bid >> 3;
  int mt = (bid >> 1) & 3;
  int nt = bid & 1;
  int s = sid[batch];

  int t = threadIdx.x;
  int l = t & 63, wv = t >> 6;
  int wm = (wv >> 1) * 64, wn = (wv & 1) * 64;  // wave origin in 128x128 tile
  int fr = l & 15;         // fragment row (A) / col (B)
  int kq = (l >> 4) * 8;   // k offset within a 32-wide k-slice
  int r0 = (l >> 4) * 4;   // C/D row group

  const float* xA =
      x + ((size_t)batch * T_DIM + mt * 128 + wm + fr) * IN_DIM + kq;
  const unsigned short* wB = wT + (size_t)s * IN_DIM * OUT_DIM +
                             (size_t)(nt * 128 + wn + fr) * IN_DIM + kq;

  f32x4 acc[4][4];
#pragma unroll
  for (int i = 0; i < 4; ++i)
#pragma unroll
    for (int j = 0; j < 4; ++j) acc[i][j] = (f32x4){0.f, 0.f, 0.f, 0.f};

  // K = 256 -> 8 k-slices of 32
#pragma unroll
  for (int ks = 0; ks < 8; ++ks) {
    int k0 = ks * 32;  // + kq already folded into base pointers
    s16x8 af[4];
    s16x8 bfr[4];
#pragma unroll
    for (int fm = 0; fm < 4; ++fm) {
      const float* p = xA + (size_t)(fm * 16) * IN_DIM + k0;
      f32x4 lo = *(const f32x4*)(p);
      f32x4 hi = *(const f32x4*)(p + 4);
      s16x8 a;
      a[0] = (short)f2bf(lo[0]); a[1] = (short)f2bf(lo[1]);
      a[2] = (short)f2bf(lo[2]); a[3] = (short)f2bf(lo[3]);
      a[4] = (short)f2bf(hi[0]); a[5] = (short)f2bf(hi[1]);
      a[6] = (short)f2bf(hi[2]); a[7] = (short)f2bf(hi[3]);
      af[fm] = a;
    }
#pragma unroll
    for (int fn = 0; fn < 4; ++fn) {
      bfr[fn] = *(const s16x8*)(wB + (size_t)(fn * 16) * IN_DIM + k0);
    }
#pragma unroll
    for (int fm = 0; fm < 4; ++fm)
#pragma unroll
      for (int fn = 0; fn < 4; ++fn)
        acc[fm][fn] = __builtin_amdgcn_mfma_f32_16x16x32_bf16(
            af[fm], bfr[fn], acc[fm][fn], 0, 0, 0);
  }

  // epilogue: add bias, store (16-lane groups write 64B contiguous)
  const float* bp = bias + (size_t)s * OUT_DIM;
  float bv[4];
#pragma unroll
  for (int fn = 0; fn < 4; ++fn) bv[fn] = bp[nt * 128 + wn + fn * 16 + fr];

  float* orow =
      out + ((size_t)batch * T_DIM + mt * 128 + wm) * OUT_DIM + nt * 128 + wn;
#pragma unroll
  for (int fm = 0; fm < 4; ++fm)
#pragma unroll
    for (int fn = 0; fn < 4; ++fn)
#pragma unroll
      for (int r = 0; r < 4; ++r)
        orow[(size_t)(fm * 16 + r0 + r) * OUT_DIM + fn * 16 + fr] =
            acc[fm][fn][r] + bv[fn];
}

// Emergency fallback if d_ws is too small: correct but slow.
__global__ __launch_bounds__(256) void naive_kernel(
    const float* __restrict__ x, const int* __restrict__ sid,
    const float* __restrict__ w, const float* __restrict__ bias,
    float* __restrict__ out) {
  __shared__ float lx[IN_DIM];
  size_t bt = blockIdx.x;
  int batch = (int)(bt / T_DIM);
  int s = sid[batch];
  int o = threadIdx.x;
  lx[o] = x[bt * IN_DIM + o];
  __syncthreads();
  const float* wp = w + (size_t)s * IN_DIM * OUT_DIM + o;
  float acc = bias[(size_t)s * OUT_DIM + o];
  for (int i = 0; i < IN_DIM; ++i) acc += lx[i] * wp[(size_t)i * OUT_DIM];
  out[bt * OUT_DIM + o] = acc;
}

extern "C" void kernel_launch(void* const* d_in, const int* in_sizes, int n_in,
                              void* d_out, int out_size, void* d_ws, size_t ws_size,
                              hipStream_t stream) {
  const float* x = (const float*)d_in[0];
  const int* sid = (const int*)d_in[1];
  const float* w = (const float*)d_in[2];
  const float* bias = (const float*)d_in[3];
  float* out = (float*)d_out;

  size_t need = (size_t)S_DIM * IN_DIM * OUT_DIM * sizeof(unsigned short);
  if (ws_size >= need) {
    unsigned short* wT = (unsigned short*)d_ws;
    wt_transpose<<<dim3(S_DIM * 16), dim3(256), 0, stream>>>(w, wT);
    subj_gemm_nl<<<dim3(2048), dim3(256), 0, stream>>>(x, sid, wT, bias, out);
  } else {
    naive_kernel<<<dim3(B_DIM * T_DIM), dim3(256), 0, stream>>>(x, sid, w, bias, out);
  }
}

// Round 3
// 89.724 us; speedup vs baseline: 1.4630x; 1.4630x over previous
//
#include <hip/hip_runtime.h>
#include <hip/hip_bf16.h>

// SubjectLayers: out[b,t,o] = sum_i x[b,t,i] * w[sid[b],i,o] + bias[sid[b],o]
// B=256 T=512 IN=256 OUT=256 S=128, all fp32 in/out.
// R3: global_load_lds double-buffered pipeline with COUNTED vmcnt (T3/T4-lite).
// A staged as f32 (convert to bf16 on fragment read), B staged from bf16 wT.
// XOR-swizzled LDS via pre-swizzled global source (linear LDS dest).

#define B_DIM 256
#define T_DIM 512
#define IN_DIM 256
#define OUT_DIM 256
#define S_DIM 128
#define BK 32

typedef __attribute__((ext_vector_type(4))) float f32x4;
typedef __attribute__((ext_vector_type(8))) short s16x8;
typedef __attribute__((ext_vector_type(8))) unsigned short u16x8;
typedef __attribute__((ext_vector_type(4))) unsigned short u16x4;

typedef const __attribute__((address_space(1))) unsigned int* gptr_t;
typedef __attribute__((address_space(3))) unsigned int* lptr_t;

static __device__ __forceinline__ unsigned short f2bf(float f) {
  __hip_bfloat16 h = __float2bfloat16(f);
  return __builtin_bit_cast(unsigned short, h);
}

// Pre-pass: wT[s][o][i] = bf16(w[s][i][o]). 64x64 tiles via LDS.
__global__ __launch_bounds__(256) void wt_transpose(const float* __restrict__ w,
                                                    unsigned short* __restrict__ wT) {
  __shared__ float tile[64][65];
  int bid = blockIdx.x;
  int s = bid >> 4, ti = (bid >> 2) & 3, to = bid & 3;
  const float* wp = w + (size_t)s * IN_DIM * OUT_DIM;
  unsigned short* op = wT + (size_t)s * IN_DIM * OUT_DIM;
  int t = threadIdx.x;
  int rr = t >> 6, cc = t & 63;
#pragma unroll
  for (int p = 0; p < 16; ++p) {
    tile[p * 4 + rr][cc] = wp[(size_t)(ti * 64 + p * 4 + rr) * OUT_DIM + to * 64 + cc];
  }
  __syncthreads();
  int orr = t >> 4, i4 = (t & 15) * 4;
#pragma unroll
  for (int p = 0; p < 4; ++p) {
    int ol = p * 16 + orr;  // o within tile
    u16x4 v;
    v[0] = f2bf(tile[i4 + 0][ol]);
    v[1] = f2bf(tile[i4 + 1][ol]);
    v[2] = f2bf(tile[i4 + 2][ol]);
    v[3] = f2bf(tile[i4 + 3][ol]);
    *(u16x4*)(op + (size_t)(to * 64 + ol) * IN_DIM + ti * 64 + i4) = v;
  }
}

// Pipelined GEMM. Block = 128 T-rows x 128 O-cols, 4 waves (2m x 2n),
// wave tile 64x64 (4x4 frags of 16x16x32 bf16 MFMA). 8 K-steps of BK=32.
// LDS content is XOR-swizzled in 16-B chunks: A chunk c holds global chunk
// c^(row&7) (rows of 128B); B chunk c holds global chunk c^(row&3) (rows 64B).
__global__ __launch_bounds__(256, 3) void subj_gemm_pipe(
    const float* __restrict__ x, const int* __restrict__ sid,
    const unsigned short* __restrict__ wT, const float* __restrict__ bias,
    float* __restrict__ out) {
  __shared__ __align__(16) float lA[2][128 * BK];           // 16 KB x2
  __shared__ __align__(16) unsigned short lB[2][128 * BK];  // 8 KB x2

  // pair-swizzle: the two nt-tiles of one (batch,mt) are grid-adjacent
  unsigned wg = blockIdx.x;
  unsigned bid = (wg & ~15u) | ((wg & 7u) << 1) | ((wg >> 3) & 1u);
  int batch = bid >> 3;
  int mt = (bid >> 1) & 3;
  int nt = bid & 1;
  int s = sid[batch];

  int t = threadIdx.x;
  int l = t & 63, wv = t >> 6;
  int wm = (wv >> 1) * 64, wn = (wv & 1) * 64;

  // staging: per-lane pre-swizzled global source, wave-uniform LDS dest
  const float* xbase = x + ((size_t)batch * T_DIM + mt * 128) * IN_DIM;
  const unsigned short* wbase =
      wT + (size_t)s * IN_DIM * OUT_DIM + (size_t)(nt * 128) * IN_DIM;
  int a_rl = l >> 3;                   // row within instr's 8 rows
  int a_cs = (l & 7) ^ (a_rl & 7);     // swizzled source chunk (16B units)
  int b_rl = l >> 2;                   // row within instr's 16 rows
  int b_cs = (l & 3) ^ (b_rl & 3);

#define STAGE_A(buf, step, i)                                                  \
  __builtin_amdgcn_global_load_lds(                                            \
      (gptr_t)(xbase + (size_t)((wv * 4 + (i)) * 8 + a_rl) * IN_DIM +          \
               (step) * BK + a_cs * 4),                                        \
      (lptr_t)&lA[buf][(wv * 4 + (i)) * 256], 16, 0, 0)
#define STAGE_B(buf, step, i)                                                  \
  __builtin_amdgcn_global_load_lds(                                            \
      (gptr_t)(wbase + (size_t)((wv * 2 + (i)) * 16 + b_rl) * IN_DIM +         \
               (step) * BK + b_cs * 8),                                        \
      (lptr_t)&lB[buf][(wv * 2 + (i)) * 512], 16, 0, 0)
#define STAGE(buf, step)                                                       \
  do {                                                                         \
    STAGE_A(buf, step, 0); STAGE_A(buf, step, 1);                              \
    STAGE_A(buf, step, 2); STAGE_A(buf, step, 3);                              \
    STAGE_B(buf, step, 0); STAGE_B(buf, step, 1);                              \
  } while (0)

  int fr = l & 15;       // fragment row/col
  int kq4 = l >> 4;      // 16B chunk-pair selector (k = kq4*8 .. +7)
  int r0 = (l >> 4) * 4; // C/D row group

  f32x4 acc[4][4];
#pragma unroll
  for (int i = 0; i < 4; ++i)
#pragma unroll
    for (int j = 0; j < 4; ++j) acc[i][j] = (f32x4){0.f, 0.f, 0.f, 0.f};

  STAGE(0, 0);  // 6 loads/wave
  STAGE(1, 1);  // 6 loads/wave

#pragma unroll
  for (int step = 0; step < 8; ++step) {
    const int bf = step & 1;
    // wait for tile `step` (leave next stage's 6 loads in flight)
    if (step < 7) asm volatile("s_waitcnt vmcnt(6)" ::: "memory");
    else          asm volatile("s_waitcnt vmcnt(0)" ::: "memory");
    __builtin_amdgcn_s_barrier();
    asm volatile("" ::: "memory");

    s16x8 afrag[4], bfrag[4];
#pragma unroll
    for (int fm = 0; fm < 4; ++fm) {
      int row = wm + fm * 16 + fr;
      int c0 = (kq4 * 2) ^ (row & 7);
      int c1 = (kq4 * 2 + 1) ^ (row & 7);
      f32x4 lo = *(const f32x4*)&lA[bf][row * 32 + c0 * 4];
      f32x4 hi = *(const f32x4*)&lA[bf][row * 32 + c1 * 4];
      s16x8 a;
      a[0] = (short)f2bf(lo[0]); a[1] = (short)f2bf(lo[1]);
      a[2] = (short)f2bf(lo[2]); a[3] = (short)f2bf(lo[3]);
      a[4] = (short)f2bf(hi[0]); a[5] = (short)f2bf(hi[1]);
      a[6] = (short)f2bf(hi[2]); a[7] = (short)f2bf(hi[3]);
      afrag[fm] = a;
    }
#pragma unroll
    for (int fn = 0; fn < 4; ++fn) {
      int row = wn + fn * 16 + fr;
      int c = kq4 ^ (row & 3);
      bfrag[fn] = *(const s16x8*)&lB[bf][row * 32 + c * 8];
    }
#pragma unroll
    for (int fm = 0; fm < 4; ++fm)
#pragma unroll
      for (int fn = 0; fn < 4; ++fn)
        acc[fm][fn] = __builtin_amdgcn_mfma_f32_16x16x32_bf16(
            afrag[fm], bfrag[fn], acc[fm][fn], 0, 0, 0);

    asm volatile("" ::: "memory");
    __builtin_amdgcn_s_barrier();  // all waves done reading buf[bf]
    if (step < 6) STAGE(step & 1, step + 2);  // overwrite buf[bf] for step+2
  }

  // epilogue: add bias, store (16-lane groups write 64B contiguous)
  const float* bp = bias + (size_t)s * OUT_DIM;
  float bv[4];
#pragma unroll
  for (int fn = 0; fn < 4; ++fn) bv[fn] = bp[nt * 128 + wn + fn * 16 + fr];

  float* orow =
      out + ((size_t)batch * T_DIM + mt * 128 + wm) * OUT_DIM + nt * 128 + wn;
#pragma unroll
  for (int fm = 0; fm < 4; ++fm)
#pragma unroll
    for (int fn = 0; fn < 4; ++fn)
#pragma unroll
      for (int r = 0; r < 4; ++r)
        orow[(size_t)(fm * 16 + r0 + r) * OUT_DIM + fn * 16 + fr] =
            acc[fm][fn][r] + bv[fn];
#undef STAGE
#undef STAGE_A
#undef STAGE_B
}

// Emergency fallback if d_ws is too small: correct but slow.
__global__ __launch_bounds__(256) void naive_kernel(
    const float* __restrict__ x, const int* __restrict__ sid,
    const float* __restrict__ w, const float* __restrict__ bias,
    float* __restrict__ out) {
  __shared__ float lx[IN_DIM];
  size_t bt = blockIdx.x;
  int batch = (int)(bt / T_DIM);
  int s = sid[batch];
  int o = threadIdx.x;
  lx[o] = x[bt * IN_DIM + o];
  __syncthreads();
  const float* wp = w + (size_t)s * IN_DIM * OUT_DIM + o;
  float acc = bias[(size_t)s * OUT_DIM + o];
  for (int i = 0; i < IN_DIM; ++i) acc += lx[i] * wp[(size_t)i * OUT_DIM];
  out[bt * OUT_DIM + o] = acc;
}

extern "C" void kernel_launch(void* const* d_in, const int* in_sizes, int n_in,
                              void* d_out, int out_size, void* d_ws, size_t ws_size,
                              hipStream_t stream) {
  const float* x = (const float*)d_in[0];
  const int* sid = (const int*)d_in[1];
  const float* w = (const float*)d_in[2];
  const float* bias = (const float*)d_in[3];
  float* out = (float*)d_out;

  size_t need = (size_t)S_DIM * IN_DIM * OUT_DIM * sizeof(unsigned short);
  if (ws_size >= need) {
    unsigned short* wT = (unsigned short*)d_ws;
    wt_transpose<<<dim3(S_DIM * 16), dim3(256), 0, stream>>>(w, wT);
    subj_gemm_pipe<<<dim3(2048), dim3(256), 0, stream>>>(x, sid, wT, bias, out);
  } else {
    naive_kernel<<<dim3(B_DIM * T_DIM), dim3(256), 0, stream>>>(x, sid, w, bias, out);
  }
}